// Round 1
// baseline (1003.332 us; speedup 1.0000x reference)
//
#include <hip/hip_runtime.h>
#include <stdint.h>

// Problem constants (Experts FFN): E experts, C tokens/expert, D model, F ff
#define E_ 8
#define C_ 4096
#define D_ 1024
#define F_ 4096

typedef __attribute__((ext_vector_type(8))) short bf16x8;
typedef __attribute__((ext_vector_type(4))) float f32x4;
typedef __attribute__((ext_vector_type(8))) unsigned short u16x8;

__device__ __forceinline__ unsigned short f2bf(float x) {
  union { float f; uint32_t u; } v; v.f = x;
  uint32_t r = v.u + 0x7FFFu + ((v.u >> 16) & 1u);  // RNE
  return (unsigned short)(r >> 16);
}

// JAX gelu (approximate=True): 0.5*x*(1+tanh(sqrt(2/pi)*(x+0.044715*x^3)))
__device__ __forceinline__ float gelu_f(float x) {
  float x3 = x * x * x;
  float u = 0.7978845608028654f * __builtin_fmaf(0.044715f, x3, x);
  float t = __expf(2.0f * u);               // e^{2u}; inf-safe
  float th = 1.0f - 2.0f / (t + 1.0f);      // tanh(u)
  return 0.5f * x * (1.0f + th);
}

// ---------------- elementwise fp32 -> bf16 ----------------
__global__ void convert_bf16_kernel(const float* __restrict__ in,
                                    unsigned short* __restrict__ out, size_t n) {
  size_t i = ((size_t)blockIdx.x * blockDim.x + threadIdx.x) * 8;
  size_t stride = (size_t)gridDim.x * blockDim.x * 8;
  for (; i < n; i += stride) {
    float4 a = *(const float4*)(in + i);
    float4 b = *(const float4*)(in + i + 4);
    u16x8 o;
    o[0] = f2bf(a.x); o[1] = f2bf(a.y); o[2] = f2bf(a.z); o[3] = f2bf(a.w);
    o[4] = f2bf(b.x); o[5] = f2bf(b.y); o[6] = f2bf(b.z); o[7] = f2bf(b.w);
    *(u16x8*)(out + i) = o;
  }
}

// ---------------- tiled transpose: fp32 [K][N] -> bf16 [N][K] ----------------
__global__ void transpose_bf16_kernel(const float* __restrict__ in,
                                      unsigned short* __restrict__ out,
                                      int K, int N) {
  const int ge = blockIdx.z;
  const float* src = in + (size_t)ge * K * N;
  unsigned short* dst = out + (size_t)ge * K * N;
  __shared__ float tile[32][33];  // +1 pad: conflict-free both directions
  int t = threadIdx.x;
  int tx = t & 31, ty = t >> 5;   // 32 x 8
  int k0 = blockIdx.x * 32, n0 = blockIdx.y * 32;
#pragma unroll
  for (int p = 0; p < 4; ++p)
    tile[ty + p * 8][tx] = src[(size_t)(k0 + ty + p * 8) * N + n0 + tx];
  __syncthreads();
#pragma unroll
  for (int p = 0; p < 4; ++p)
    dst[(size_t)(n0 + ty + p * 8) * K + k0 + tx] = f2bf(tile[tx][ty + p * 8]);
}

// ---------------- async global->LDS (CK-style casts) ----------------
typedef const __attribute__((address_space(1))) uint32_t* gas1_ptr;
typedef __attribute__((address_space(3))) uint32_t* las3_ptr;

__device__ __forceinline__ void async16(const void* g, void* l) {
  __builtin_amdgcn_global_load_lds((gas1_ptr)(uintptr_t)g, (las3_ptr)(uintptr_t)l,
                                   16, 0, 0);
}

// ---------------- bf16 GEMM: C[M][N] = A[M][K] * B[N][K]^T (+bias) ----------------
// MODE 0: out fp32 (Y = acc + bias); MODE 1: out bf16 (H = gelu(acc + bias))
// m97 structure: BM=128, BK=64, 256 thr (4 waves, 2x2), 16x16x32 bf16 MFMA,
// global_load_lds w=16, XOR-swizzled LDS via pre-swizzled global source (m173).
template <int BN, int MODE>
__global__ __launch_bounds__(256) void gemm_kernel(
    const unsigned short* __restrict__ A,  // [M][K] bf16
    const unsigned short* __restrict__ B,  // [N][K] bf16 (transposed weight)
    const float* __restrict__ bias,        // [N]
    void* __restrict__ Cout,
    int K, int N,
    size_t aStride, size_t bStride, size_t cStride, int biasStride) {
  constexpr int BM = 128, BK = 64;
  constexpr int NF = BN / 32;  // n-frags per wave ((BN/2)/16)
  const int ge = blockIdx.z;
  A += (size_t)ge * aStride;
  B += (size_t)ge * bStride;
  bias += (size_t)ge * biasStride;

  const int t = threadIdx.x;
  const int lane = t & 63;
  const int w = t >> 6;                    // wave 0..3
  const int wm = w & 1, wn = w >> 1;       // 2x2 wave grid
  const int l15 = lane & 15, q = lane >> 4;

  const int rowTile = blockIdx.x * BM;
  const int colTile = blockIdx.y * BN;

  __shared__ unsigned short As[BM * BK];
  __shared__ unsigned short Bs[BN * BK];
  char* As_c = (char*)As;
  char* Bs_c = (char*)Bs;

  f32x4 acc[4][NF];
#pragma unroll
  for (int m = 0; m < 4; ++m)
#pragma unroll
    for (int n = 0; n < NF; ++n) acc[m][n] = {0.f, 0.f, 0.f, 0.f};

  constexpr int nIterA = (BM * 8) / 256;  // 4 wave-issues of 64 lanes
  constexpr int nIterB = (BN * 8) / 256;  // 4 (BN=128) or 2 (BN=64)
  const size_t ldBytes = (size_t)K * 2;   // both A and B have row stride K

  for (int kt = 0; kt < K; kt += BK) {
    __syncthreads();  // previous tile fully consumed
    // stage A: chunk u -> (row=u>>3, kc=u&7); source pre-swizzled kc^(row&7)
#pragma unroll
    for (int j = 0; j < nIterA; ++j) {
      int u = (w * nIterA + j) * 64 + lane;
      int r = u >> 3, kc = u & 7;
      const char* src = (const char*)A + (size_t)(rowTile + r) * ldBytes +
                        (size_t)kt * 2 + ((kc ^ (r & 7)) << 4);
      async16(src, (void*)(As_c + (size_t)(w * nIterA + j) * 1024));
    }
#pragma unroll
    for (int j = 0; j < nIterB; ++j) {
      int u = (w * nIterB + j) * 64 + lane;
      int r = u >> 3, kc = u & 7;
      const char* src = (const char*)B + (size_t)(colTile + r) * ldBytes +
                        (size_t)kt * 2 + ((kc ^ (r & 7)) << 4);
      async16(src, (void*)(Bs_c + (size_t)(w * nIterB + j) * 1024));
    }
    __syncthreads();  // drains vmcnt, loads visible

#pragma unroll
    for (int ks = 0; ks < 2; ++ks) {
      bf16x8 af[4], bfr[NF];
#pragma unroll
      for (int m = 0; m < 4; ++m) {
        int r = wm * 64 + m * 16 + l15;
        af[m] = *(const bf16x8*)(As_c + r * 128 +
                                 ((ks * 64 + q * 16) ^ ((r & 7) << 4)));
      }
#pragma unroll
      for (int n = 0; n < NF; ++n) {
        int r = wn * (BN / 2) + n * 16 + l15;
        bfr[n] = *(const bf16x8*)(Bs_c + r * 128 +
                                  ((ks * 64 + q * 16) ^ ((r & 7) << 4)));
      }
#pragma unroll
      for (int m = 0; m < 4; ++m)
#pragma unroll
        for (int n = 0; n < NF; ++n)
          acc[m][n] = __builtin_amdgcn_mfma_f32_16x16x32_bf16(af[m], bfr[n],
                                                              acc[m][n], 0, 0, 0);
    }
  }

  // epilogue; C/D layout (m89): col = lane&15, row = (lane>>4)*4 + j
#pragma unroll
  for (int n = 0; n < NF; ++n) {
    int col = colTile + wn * (BN / 2) + n * 16 + l15;
    float bv = bias[col];
#pragma unroll
    for (int m = 0; m < 4; ++m) {
      int r0 = rowTile + wm * 64 + m * 16 + q * 4;
      f32x4 v = acc[m][n];
#pragma unroll
      for (int j = 0; j < 4; ++j) {
        float x = v[j] + bv;
        if constexpr (MODE == 1) {
          ((unsigned short*)Cout)[ge * cStride + (size_t)(r0 + j) * N + col] =
              f2bf(gelu_f(x));
        } else {
          ((float*)Cout)[ge * cStride + (size_t)(r0 + j) * N + col] = x;
        }
      }
    }
  }
}

extern "C" void kernel_launch(void* const* d_in, const int* in_sizes, int n_in,
                              void* d_out, int out_size, void* d_ws, size_t ws_size,
                              hipStream_t stream) {
  const float* X = (const float*)d_in[0];   // [1][E*C][D]
  const float* W1 = (const float*)d_in[1];  // [E][D][F]
  const float* b1 = (const float*)d_in[2];  // [E][F]
  const float* W2 = (const float*)d_in[3];  // [E][F][D]
  const float* b2 = (const float*)d_in[4];  // [E][D]
  float* Y = (float*)d_out;                 // [1][E*C][D]

  const size_t szX = (size_t)C_ * D_ * 2;   // per-expert bf16 bytes
  const size_t szW1 = (size_t)F_ * D_ * 2;
  const size_t szW2 = (size_t)D_ * F_ * 2;
  const size_t szH = (size_t)C_ * F_ * 2;
  const size_t fixed = szX + szW1 + szW2;   // 24 MB

  // group g experts per pass so GEMM grids stay >= ~1024 wgs
  int g = 0;
  {
    const int cands[4] = {8, 4, 2, 1};
    for (int i = 0; i < 4; ++i)
      if ((fixed + szH) * (size_t)cands[i] <= ws_size) { g = cands[i]; break; }
  }
  int RC = C_;
  if (g == 0) {  // tiny-ws fallback: chunk rows of H
    g = 1;
    size_t avail = ws_size > fixed ? ws_size - fixed : 0;
    RC = (int)(avail / ((size_t)F_ * 2));
    RC = (RC / 128) * 128;
    if (RC < 128) RC = 128;
    if (RC > C_) RC = C_;
  }

  unsigned short* XB = (unsigned short*)d_ws;              // [g][C][D]
  unsigned short* W1T = XB + (size_t)g * C_ * D_;          // [g][F][D]
  unsigned short* W2T = W1T + (size_t)g * F_ * D_;         // [g][D][F]
  unsigned short* H = W2T + (size_t)g * D_ * F_;           // [g][RC][F]

  for (int e0 = 0; e0 < E_; e0 += g) {
    {
      size_t n = (size_t)g * C_ * D_;
      size_t nb = (n / 8 + 255) / 256;
      if (nb > 2048) nb = 2048;
      convert_bf16_kernel<<<dim3((unsigned)nb), 256, 0, stream>>>(
          X + (size_t)e0 * C_ * D_, XB, n);
    }
    transpose_bf16_kernel<<<dim3(D_ / 32, F_ / 32, g), 256, 0, stream>>>(
        W1 + (size_t)e0 * D_ * F_, W1T, D_, F_);
    transpose_bf16_kernel<<<dim3(F_ / 32, D_ / 32, g), 256, 0, stream>>>(
        W2 + (size_t)e0 * F_ * D_, W2T, F_, D_);

    for (int r0 = 0; r0 < C_; r0 += RC) {
      // GEMM1: H = gelu(XB @ W1T^T + b1), [RC x F], K = D
      gemm_kernel<128, 1><<<dim3(RC / 128, F_ / 128, g), 256, 0, stream>>>(
          XB + (size_t)r0 * D_, W1T, b1 + (size_t)e0 * F_, (void*)H,
          D_, F_, (size_t)C_ * D_, (size_t)F_ * D_, (size_t)RC * F_, F_);
      // GEMM2: Y = H @ W2T^T + b2, [RC x D], K = F
      if (g >= 4) {
        gemm_kernel<128, 0><<<dim3(RC / 128, D_ / 128, g), 256, 0, stream>>>(
            H, W2T, b2 + (size_t)e0 * D_,
            (void*)(Y + (size_t)e0 * C_ * D_ + (size_t)r0 * D_),
            F_, D_, (size_t)RC * F_, (size_t)D_ * F_, (size_t)C_ * D_, D_);
      } else {
        gemm_kernel<64, 0><<<dim3(RC / 128, D_ / 64, g), 256, 0, stream>>>(
            H, W2T, b2 + (size_t)e0 * D_,
            (void*)(Y + (size_t)e0 * C_ * D_ + (size_t)r0 * D_),
            F_, D_, (size_t)RC * F_, (size_t)D_ * F_, (size_t)C_ * D_, D_);
      }
    }
  }
}

// Round 2
// 725.304 us; speedup vs baseline: 1.3833x; 1.3833x over previous
//
#include <hip/hip_runtime.h>
#include <stdint.h>

// Experts FFN: E experts, C tokens/expert, D model, F ff
#define E_ 8
#define C_ 4096
#define D_ 1024
#define F_ 4096

typedef __attribute__((ext_vector_type(8))) short bf16x8;
typedef __attribute__((ext_vector_type(4))) float f32x4;
typedef __attribute__((ext_vector_type(8))) unsigned short u16x8;
typedef __attribute__((ext_vector_type(4))) unsigned short u16x4;

__device__ __forceinline__ unsigned short f2bf(float x) {
  union { float f; uint32_t u; } v; v.f = x;
  uint32_t r = v.u + 0x7FFFu + ((v.u >> 16) & 1u);  // RNE
  return (unsigned short)(r >> 16);
}

// JAX gelu (approximate=True)
__device__ __forceinline__ float gelu_f(float x) {
  float x3 = x * x * x;
  float u = 0.7978845608028654f * __builtin_fmaf(0.044715f, x3, x);
  float t = __expf(2.0f * u);
  float th = 1.0f - 2.0f / (t + 1.0f);
  return 0.5f * x * (1.0f + th);
}

// ---------------- elementwise fp32 -> bf16 ----------------
__global__ void convert_bf16_kernel(const float* __restrict__ in,
                                    unsigned short* __restrict__ out, size_t n) {
  size_t i = ((size_t)blockIdx.x * blockDim.x + threadIdx.x) * 8;
  size_t stride = (size_t)gridDim.x * blockDim.x * 8;
  for (; i < n; i += stride) {
    float4 a = *(const float4*)(in + i);
    float4 b = *(const float4*)(in + i + 4);
    u16x8 o;
    o[0] = f2bf(a.x); o[1] = f2bf(a.y); o[2] = f2bf(a.z); o[3] = f2bf(a.w);
    o[4] = f2bf(b.x); o[5] = f2bf(b.y); o[6] = f2bf(b.z); o[7] = f2bf(b.w);
    *(u16x8*)(out + i) = o;
  }
}

// ---------------- tiled transpose: fp32 [K][N] -> bf16 [N][K] ----------------
__global__ void transpose_bf16_kernel(const float* __restrict__ in,
                                      unsigned short* __restrict__ out,
                                      int K, int N) {
  const int ge = blockIdx.z;
  const float* src = in + (size_t)ge * K * N;
  unsigned short* dst = out + (size_t)ge * K * N;
  __shared__ float tile[32][33];
  int t = threadIdx.x;
  int tx = t & 31, ty = t >> 5;  // 32 x 8
  int k0 = blockIdx.x * 32, n0 = blockIdx.y * 32;
#pragma unroll
  for (int p = 0; p < 4; ++p)
    tile[ty + p * 8][tx] = src[(size_t)(k0 + ty + p * 8) * N + n0 + tx];
  __syncthreads();
#pragma unroll
  for (int p = 0; p < 4; ++p)
    dst[(size_t)(n0 + ty + p * 8) * K + k0 + tx] = f2bf(tile[tx][ty + p * 8]);
}

// ---------------- async global->LDS ----------------
typedef const __attribute__((address_space(1))) uint32_t* gas1_ptr;
typedef __attribute__((address_space(3))) uint32_t* las3_ptr;

__device__ __forceinline__ void async16(const void* g, void* l) {
  __builtin_amdgcn_global_load_lds((gas1_ptr)(uintptr_t)g, (las3_ptr)(uintptr_t)l,
                                   16, 0, 0);
}

// ============================================================================
// 256x256 8-phase bf16 GEMM (m201 structure, plain HIP):
//   C[M][N] = A[M][K] * B[N][K]^T (+bias) ; MODE 0: fp32 out; MODE 1: bf16 gelu
// 512 thr = 8 waves (2M x 4N), per-wave 128x64, BK=64, LDS 128 KiB 2-dbuf.
// Halves: A-half h = rows with bit6==h (i.e. each wave's mf0-3 / mf4-7);
//         B-half h = cols with bit5==h (each wave's nf0-1 / nf2-3).
// Phase quadrant order per K-tile: (0,0),(0,1),(1,1),(1,0); B-frags of nh=0
// kept in regs from ph1 to ph4, so region last-reads are A0:ph1 B0:ph1
// B1:ph2 A1:ph3 -> staging targets region freed one phase earlier.
// vmcnt(6) only at ph4/ph8 => 3 half-tiles (6 loads) in flight, loads retire
// in order, all deadlines checked.
// Swapped MFMA operands (mfma(b,a)): lane l15 -> M row, (q*4+j) -> N col,
// so epilogue stores are float4 / ushort4 packed.
// ============================================================================

#define SYNC_PRE() do { \
    __builtin_amdgcn_sched_barrier(0); \
    __builtin_amdgcn_s_barrier(); \
    asm volatile("s_waitcnt lgkmcnt(0)" ::: "memory"); \
    __builtin_amdgcn_sched_barrier(0); \
    __builtin_amdgcn_s_setprio(1); \
  } while (0)

#define SYNC_POST() do { \
    __builtin_amdgcn_s_setprio(0); \
    __builtin_amdgcn_sched_barrier(0); \
    __builtin_amdgcn_s_barrier(); \
    __builtin_amdgcn_sched_barrier(0); \
  } while (0)

#define SYNC_POST_VM() do { \
    __builtin_amdgcn_s_setprio(0); \
    __builtin_amdgcn_sched_barrier(0); \
    asm volatile("s_waitcnt vmcnt(6)" ::: "memory"); \
    __builtin_amdgcn_s_barrier(); \
    __builtin_amdgcn_sched_barrier(0); \
  } while (0)

template <int MODE>
__global__ __launch_bounds__(512, 2) void gemm256_kernel(
    const unsigned short* __restrict__ A,  // [M][K] bf16
    const unsigned short* __restrict__ B,  // [N][K] bf16
    const float* __restrict__ bias,        // [N]
    void* __restrict__ Cout,
    int K, int N, int numM, int numN,
    size_t aStride, size_t bStride, size_t cStride, int biasStride) {
  __shared__ char lds[131072];
  char* ldsp = (char*)lds;

  const int NT = K >> 6;      // 64-wide K tiles (K % 128 == 0 here)
  const int NITER = NT >> 1;

  // bijective XCD swizzle (m204)
  int lin = blockIdx.x;
  int nwg = gridDim.x;
  int qq = nwg >> 3, rr8 = nwg & 7;
  int xcd = lin & 7, idx = lin >> 3;
  int wg = (xcd < rr8 ? xcd * (qq + 1) : rr8 * (qq + 1) + (xcd - rr8) * qq) + idx;
  int per = numM * numN;
  int e = wg / per;
  int rem = wg - e * per;
  int tm = rem % numM, tn = rem / numM;

  A += (size_t)e * aStride;
  B += (size_t)e * bStride;
  bias += (size_t)e * biasStride;

  const int rowTile = tm << 8;
  const int colTile = tn << 8;

  const int tid = threadIdx.x;
  const int lane = tid & 63;
  const int w = tid >> 6;
  const int wm = w & 1, wn = w >> 1;
  const int l15 = lane & 15, q = lane >> 4;

  const size_t ldB = (size_t)K * 2;  // row bytes for A and B

  // ---- staging precompute (per-thread, loop-invariant) ----
  const int rlo = tid >> 3, kc = tid & 7;
  const int swzsrc = ((kc ^ (rlo & 7)) << 4);      // pre-swizzled global chunk
  const char* aS0 = (const char*)A + (size_t)(rowTile + rlo) * ldB + swzsrc;
  const char* aS1 = (const char*)A + (size_t)(rowTile + rlo + 128) * ldB + swzsrc;
  const int bcol = (rlo & 31) + ((rlo >> 5) << 6);
  const char* bS0 = (const char*)B + (size_t)(colTile + bcol) * ldB + swzsrc;
  const char* bS1 = (const char*)B + (size_t)(colTile + bcol + 128) * ldB + swzsrc;
  const size_t a64 = (size_t)64 * ldB;   // A-half stride (rows +64)
  const size_t b32 = (size_t)32 * ldB;   // B-half stride (cols +32)
  const int aD0 = rlo * 128 + kc * 16;
  const int aD1 = aD0 + 16384;
  const int bD0 = 32768 + bcol * 128 + kc * 16;
  const int bD1 = bD0 + 16384;

#define STAGE_A(bb, Ah, kt) do { \
    size_t kb = (size_t)(kt) * 128; \
    int dbase = (bb) * 65536 + (Ah) * 8192; \
    async16(aS0 + (Ah) * a64 + kb, ldsp + dbase + aD0); \
    async16(aS1 + (Ah) * a64 + kb, ldsp + dbase + aD1); \
  } while (0)

#define STAGE_B(bb, Bh, kt) do { \
    size_t kb = (size_t)(kt) * 128; \
    int dbase = (bb) * 65536 + (Bh) * 4096; \
    async16(bS0 + (Bh) * b32 + kb, ldsp + dbase + bD0); \
    async16(bS1 + (Bh) * b32 + kb, ldsp + dbase + bD1); \
  } while (0)

  // ---- LDS read bases (k-offset = (q*16 ^ swz) XOR ks*64; XOR not add!) ----
  const int k0 = (q * 16) ^ ((l15 & 7) << 4);
  const int aRdBase = wm * 16384 + l15 * 128;           // + b*65536 + mf*2048
  const int bRdBase = 32768 + wn * 8192 + l15 * 128;    // + b*65536 + nf*2048

  bf16x8 aR[4][2], bR0[2][2], bR1[2][2];
  f32x4 acc[8][4];
#pragma unroll
  for (int m = 0; m < 8; ++m)
#pragma unroll
    for (int n = 0; n < 4; ++n) acc[m][n] = {0.f, 0.f, 0.f, 0.f};

#define READ_A(bb, mh) do { \
    _Pragma("unroll") for (int m4 = 0; m4 < 4; ++m4) \
    _Pragma("unroll") for (int ks = 0; ks < 2; ++ks) \
      aR[m4][ks] = *(const bf16x8*)(ldsp + (bb) * 65536 + aRdBase + \
                                    ((mh) * 4 + m4) * 2048 + (k0 ^ (ks << 6))); \
  } while (0)

#define READ_B(dst, bb, nh) do { \
    _Pragma("unroll") for (int n2 = 0; n2 < 2; ++n2) \
    _Pragma("unroll") for (int ks = 0; ks < 2; ++ks) \
      dst[n2][ks] = *(const bf16x8*)(ldsp + (bb) * 65536 + bRdBase + \
                                     ((nh) * 2 + n2) * 2048 + (k0 ^ (ks << 6))); \
  } while (0)

#define MFMA_QUAD(mh, nh, BR) do { \
    _Pragma("unroll") for (int m4 = 0; m4 < 4; ++m4) \
    _Pragma("unroll") for (int n2 = 0; n2 < 2; ++n2) \
    _Pragma("unroll") for (int ks = 0; ks < 2; ++ks) \
      acc[(mh) * 4 + m4][(nh) * 2 + n2] = \
          __builtin_amdgcn_mfma_f32_16x16x32_bf16( \
              BR[n2][ks], aR[m4][ks], acc[(mh) * 4 + m4][(nh) * 2 + n2], 0, 0, 0); \
  } while (0)

  // ---- prologue: tile0 -> buf0 (all 4 halves), tile1 -> buf1 (A0,B0,A1) ----
  STAGE_A(0, 0, 0); STAGE_B(0, 0, 0); STAGE_A(0, 1, 0); STAGE_B(0, 1, 0);
  STAGE_A(1, 0, 1); STAGE_B(1, 0, 1); STAGE_A(1, 1, 1);
  asm volatile("s_waitcnt vmcnt(6)" ::: "memory");  // tile0 landed
  __builtin_amdgcn_sched_barrier(0);
  __builtin_amdgcn_s_barrier();
  __builtin_amdgcn_sched_barrier(0);

  for (int j = 0; j < NITER; ++j) {
    int t1 = 2 * j + 1;
    int t2 = 2 * j + 2; if (t2 > NT - 1) t2 = NT - 1;  // clamped dummy stages
    int t3 = 2 * j + 3; if (t3 > NT - 1) t3 = NT - 1;  // land in freed regions

    // ph1: buf0 quad(0,0); stage buf1.B1 <- t1
    READ_A(0, 0); READ_B(bR0, 0, 0);
    STAGE_B(1, 1, t1);
    SYNC_PRE(); MFMA_QUAD(0, 0, bR0); SYNC_POST();
    // ph2: buf0 quad(0,1); stage buf0.A0 <- t2  (A0 freed after ph1)
    READ_B(bR1, 0, 1);
    STAGE_A(0, 0, t2);
    SYNC_PRE(); MFMA_QUAD(0, 1, bR1); SYNC_POST();
    // ph3: buf0 quad(1,1); stage buf0.B0 <- t2  (B0 LDS-freed after ph1)
    READ_A(0, 1);
    STAGE_B(0, 0, t2);
    SYNC_PRE(); MFMA_QUAD(1, 1, bR1); SYNC_POST();
    // ph4: buf0 quad(1,0) (regs only); stage buf0.A1 <- t2; vmcnt(6)
    STAGE_A(0, 1, t2);
    SYNC_PRE(); MFMA_QUAD(1, 0, bR0); SYNC_POST_VM();
    // ph5: buf1 quad(0,0); stage buf0.B1 <- t2  (B1 freed after ph2)
    READ_A(1, 0); READ_B(bR0, 1, 0);
    STAGE_B(0, 1, t2);
    SYNC_PRE(); MFMA_QUAD(0, 0, bR0); SYNC_POST();
    // ph6: buf1 quad(0,1); stage buf1.A0 <- t3
    READ_B(bR1, 1, 1);
    STAGE_A(1, 0, t3);
    SYNC_PRE(); MFMA_QUAD(0, 1, bR1); SYNC_POST();
    // ph7: buf1 quad(1,1); stage buf1.B0 <- t3
    READ_A(1, 1);
    STAGE_B(1, 0, t3);
    SYNC_PRE(); MFMA_QUAD(1, 1, bR1); SYNC_POST();
    // ph8: buf1 quad(1,0); stage buf1.A1 <- t3; vmcnt(6)
    STAGE_A(1, 1, t3);
    SYNC_PRE(); MFMA_QUAD(1, 0, bR0); SYNC_POST_VM();
  }
  asm volatile("s_waitcnt vmcnt(0)" ::: "memory");  // drain dummy stages

  // ---- epilogue: swapped layout => lane l15 = row, q*4+j = col ----
#pragma unroll
  for (int mf = 0; mf < 8; ++mf) {
    int row = rowTile + wm * 128 + mf * 16 + l15;
#pragma unroll
    for (int nf = 0; nf < 4; ++nf) {
      int col = colTile + wn * 64 + nf * 16 + q * 4;
      float4 bv = *(const float4*)(bias + col);
      f32x4 v = acc[mf][nf];
      if constexpr (MODE == 1) {
        u16x4 o;
        o[0] = f2bf(gelu_f(v[0] + bv.x));
        o[1] = f2bf(gelu_f(v[1] + bv.y));
        o[2] = f2bf(gelu_f(v[2] + bv.z));
        o[3] = f2bf(gelu_f(v[3] + bv.w));
        *(u16x4*)((unsigned short*)Cout + (size_t)e * cStride +
                  (size_t)row * N + col) = o;
      } else {
        float4 o;
        o.x = v[0] + bv.x; o.y = v[1] + bv.y;
        o.z = v[2] + bv.z; o.w = v[3] + bv.w;
        *(float4*)((float*)Cout + (size_t)e * cStride + (size_t)row * N + col) = o;
      }
    }
  }
}

extern "C" void kernel_launch(void* const* d_in, const int* in_sizes, int n_in,
                              void* d_out, int out_size, void* d_ws, size_t ws_size,
                              hipStream_t stream) {
  const float* X = (const float*)d_in[0];   // [1][E*C][D]
  const float* W1 = (const float*)d_in[1];  // [E][D][F]
  const float* b1 = (const float*)d_in[2];  // [E][F]
  const float* W2 = (const float*)d_in[3];  // [E][F][D]
  const float* b2 = (const float*)d_in[4];  // [E][D]
  float* Y = (float*)d_out;                 // [1][E*C][D]

  const size_t szX = (size_t)C_ * D_ * 2;
  const size_t szW1 = (size_t)F_ * D_ * 2;
  const size_t szW2 = (size_t)D_ * F_ * 2;
  const size_t szH = (size_t)C_ * F_ * 2;
  const size_t fixed = szX + szW1 + szW2;

  int g = 0;
  {
    const int cands[4] = {8, 4, 2, 1};
    for (int i = 0; i < 4; ++i)
      if ((fixed + szH) * (size_t)cands[i] <= ws_size) { g = cands[i]; break; }
  }
  int RC = C_;
  if (g == 0) {  // tiny-ws fallback: chunk rows (256-granular for BM=256)
    g = 1;
    size_t avail = ws_size > fixed ? ws_size - fixed : 0;
    RC = (int)(avail / ((size_t)F_ * 2));
    RC = (RC / 256) * 256;
    if (RC < 256) RC = 256;
    if (RC > C_) RC = C_;
  }

  unsigned short* XB = (unsigned short*)d_ws;              // [g][C][D]
  unsigned short* W1T = XB + (size_t)g * C_ * D_;          // [g][F][D]
  unsigned short* W2T = W1T + (size_t)g * F_ * D_;         // [g][D][F]
  unsigned short* H = W2T + (size_t)g * D_ * F_;           // [g][RC][F]

  const int numN1 = F_ / 256;  // 16
  const int numN2 = D_ / 256;  // 4

  for (int e0 = 0; e0 < E_; e0 += g) {
    {
      size_t n = (size_t)g * C_ * D_;
      size_t nb = (n / 8 + 255) / 256;
      if (nb > 2048) nb = 2048;
      convert_bf16_kernel<<<dim3((unsigned)nb), 256, 0, stream>>>(
          X + (size_t)e0 * C_ * D_, XB, n);
    }
    transpose_bf16_kernel<<<dim3(D_ / 32, F_ / 32, g), 256, 0, stream>>>(
        W1 + (size_t)e0 * D_ * F_, W1T, D_, F_);
    transpose_bf16_kernel<<<dim3(F_ / 32, D_ / 32, g), 256, 0, stream>>>(
        W2 + (size_t)e0 * F_ * D_, W2T, F_, D_);

    for (int r0 = 0; r0 < C_; r0 += RC) {
      int numM = RC / 256;
      // GEMM1: H = gelu(XB @ W1T^T + b1), [RC x F], K = D
      gemm256_kernel<1><<<dim3((unsigned)(numM * numN1 * g)), 512, 0, stream>>>(
          XB + (size_t)r0 * D_, W1T, b1 + (size_t)e0 * F_, (void*)H,
          D_, F_, numM, numN1,
          (size_t)C_ * D_, (size_t)F_ * D_, (size_t)RC * F_, F_);
      // GEMM2: Y = H @ W2T^T + b2, [RC x D], K = F
      gemm256_kernel<0><<<dim3((unsigned)(numM * numN2 * g)), 512, 0, stream>>>(
          H, W2T, b2 + (size_t)e0 * D_,
          (void*)(Y + (size_t)e0 * C_ * D_ + (size_t)r0 * D_),
          F_, D_, numM, numN2,
          (size_t)RC * F_, (size_t)D_ * F_, (size_t)C_ * D_, D_);
    }
  }
}